// Round 3
// baseline (424.593 us; speedup 1.0000x reference)
//
#include <hip/hip_runtime.h>
#include <stdint.h>

#define OUT_DIM 8192
#define IN_DIM  8192
#define GS      128
#define MROWS   32
#define NSPLIT  8          // split-K chunks of 1024
#define PART_ELEMS (MROWS * OUT_DIM)

typedef __attribute__((ext_vector_type(8))) short bf16x8;   // MFMA A/B frag (4 VGPR)
typedef __attribute__((ext_vector_type(4))) float f32x4;    // MFMA C/D frag
typedef __attribute__((ext_vector_type(8))) unsigned short u16x8;

__device__ __forceinline__ unsigned short f2bf_rne(float f) {
    uint32_t v = __builtin_bit_cast(uint32_t, f);
    v += 0x7FFFu + ((v >> 16) & 1u);
    return (unsigned short)(v >> 16);
}

// Pack 8 fp32 -> bf16x8 A-fragment (same bits the old prep_xbf produced).
__device__ __forceinline__ bf16x8 pack8(float4 a, float4 b) {
    u16x8 u;
    u[0] = f2bf_rne(a.x); u[1] = f2bf_rne(a.y);
    u[2] = f2bf_rne(a.z); u[3] = f2bf_rne(a.w);
    u[4] = f2bf_rne(b.x); u[5] = f2bf_rne(b.y);
    u[6] = f2bf_rne(b.z); u[7] = f2bf_rne(b.w);
    return __builtin_bit_cast(bf16x8, u);
}

// part[kc][t][o] = sum_{k in chunk kc} x[t][k] * ternary[o][k] * scale[o*64 + k/128]
// Wave: 16 o-cols x 32 t-rows (two 16x16x32 bf16 MFMA accs), K-chunk 1024.
// Round-0 body (measured ~40 us, ~95% of the 42 us HBM floor for the 256 MiB
// ternary stream) with ONE change: A-fragments are built from fp32 x directly
// (x is 1 MB, L2-resident; pack VALU hides under the HBM stream). This deletes
// the prep_xbf dispatch + xbf workspace round-trip.
// NOTE: deliberately NO min-waves clause — forcing (256,4) in round 1 caused
// spills and a +28 us regression. Compiler-chosen VGPR count wins here.
__global__ __launch_bounds__(256) void ternary_gemm(
    const int* __restrict__ tern, const float* __restrict__ scales,
    const float* __restrict__ x, float* __restrict__ part) {
    const int wave  = blockIdx.x * 4 + (threadIdx.x >> 6);
    const int lane  = threadIdx.x & 63;
    const int kc    = wave >> 9;     // 0..7   split-K chunk
    const int ntile = wave & 511;    // 0..511 o-tile
    const int n     = lane & 15;
    const int quad  = lane >> 4;
    const int o      = (ntile << 4) + n;
    const int k0base = kc << 10;

    const int* __restrict__ wrow = tern + (size_t)o * IN_DIM;
    const float* __restrict__ xr0 = x + n * IN_DIM;         // x row n (fp32)
    const float* __restrict__ xr1 = x + (16 + n) * IN_DIM;  // x row 16+n (fp32)

    // 8 contiguous group scales for this (o, kc); pipeline one it ahead.
    const float* __restrict__ sp = scales + o * (IN_DIM / GS) + (kc << 3);
    float s_cur = sp[0];

    f32x4 acc0 = {0.f, 0.f, 0.f, 0.f};
    f32x4 acc1 = {0.f, 0.f, 0.f, 0.f};

#pragma unroll 1   // keep outer loop rolled: full 8x unroll would blow VGPRs
    for (int it = 0; it < 8; ++it) {
        const unsigned int p = f2bf_rne(s_cur);          // +bf16(s)
        float s_nxt = sp[(it < 7) ? (it + 1) : 7];       // prefetch (L1-hot)
        const int k0 = k0base + (it << 7);               // 128-aligned -> one group
#pragma unroll
        for (int st = 0; st < 4; ++st) {
            const int k = k0 + (st << 5) + (quad << 3);  // lane's 8 consecutive k
            int4 w0 = *(const int4*)(wrow + k);
            int4 w1 = *(const int4*)(wrow + k + 4);
            float4 xf00 = *(const float4*)(xr0 + k);
            float4 xf01 = *(const float4*)(xr0 + k + 4);
            float4 xf10 = *(const float4*)(xr1 + k);
            float4 xf11 = *(const float4*)(xr1 + k + 4);
            bf16x8 a0 = pack8(xf00, xf01);
            bf16x8 a1 = pack8(xf10, xf11);
            int tw[8] = {w0.x, w0.y, w0.z, w0.w, w1.x, w1.y, w1.z, w1.w};
            bf16x8 bfr;
#pragma unroll
            for (int j = 0; j < 8; ++j) {
                int t = tw[j];
                // t in {-1,0,1}: (t & 0x8000) is the sign bit iff t==-1.
                unsigned int v = p | ((unsigned int)t & 0x8000u);
                bfr[j] = (short)((t == 0) ? 0u : v);
            }
            acc0 = __builtin_amdgcn_mfma_f32_16x16x32_bf16(a0, bfr, acc0, 0, 0, 0);
            acc1 = __builtin_amdgcn_mfma_f32_16x16x32_bf16(a1, bfr, acc1, 0, 0, 0);
        }
        s_cur = s_nxt;
    }

    // D layout: col = lane&15 (=o), row t = quad*4 + reg. Plain stores.
    float* __restrict__ prow = part + (size_t)kc * PART_ELEMS;
#pragma unroll
    for (int r = 0; r < 4; ++r) {
        prow[(quad * 4 + r) * OUT_DIM + o]        = acc0[r];
        prow[(quad * 4 + r + 16) * OUT_DIM + o]   = acc1[r];
    }
}

// out = sum over 8 split-K partials. 256 blocks x 256 thr x float4.
__global__ __launch_bounds__(256) void reduce_parts(const float* __restrict__ part,
                                                    float* __restrict__ out) {
    const int i = (blockIdx.x * 256 + threadIdx.x) * 4;
    float4 s = *(const float4*)(part + i);
#pragma unroll
    for (int kc = 1; kc < NSPLIT; ++kc) {
        float4 v = *(const float4*)(part + (size_t)kc * PART_ELEMS + i);
        s.x += v.x; s.y += v.y; s.z += v.z; s.w += v.w;
    }
    *(float4*)(out + i) = s;
}

extern "C" void kernel_launch(void* const* d_in, const int* in_sizes, int n_in,
                              void* d_out, int out_size, void* d_ws, size_t ws_size,
                              hipStream_t stream) {
    const float* x      = (const float*)d_in[0];
    const int*   tern   = (const int*)d_in[1];
    const float* scales = (const float*)d_in[2];
    float* out = (float*)d_out;

    float* part = (float*)d_ws;                                         // 8 MB

    ternary_gemm<<<1024, 256, 0, stream>>>(tern, scales, x, part);
    reduce_parts<<<256, 256, 0, stream>>>(part, out);
}

// Round 4
// 417.662 us; speedup vs baseline: 1.0166x; 1.0166x over previous
//
#include <hip/hip_runtime.h>
#include <stdint.h>

#define OUT_DIM 8192
#define IN_DIM  8192
#define GS      128
#define MROWS   32
#define NSPLIT  16         // split-K chunks of 512 (was 8: grid-capped occupancy at 50%)
#define KCHUNK  512
#define PART_ELEMS (MROWS * OUT_DIM)

typedef __attribute__((ext_vector_type(8))) short bf16x8;   // MFMA A/B frag (4 VGPR)
typedef __attribute__((ext_vector_type(4))) float f32x4;    // MFMA C/D frag
typedef __attribute__((ext_vector_type(8))) unsigned short u16x8;

__device__ __forceinline__ unsigned short f2bf_rne(float f) {
    uint32_t v = __builtin_bit_cast(uint32_t, f);
    v += 0x7FFFu + ((v >> 16) & 1u);
    return (unsigned short)(v >> 16);
}

// Pack 8 fp32 -> bf16x8 A-fragment (bit-identical to the old prep_xbf path).
__device__ __forceinline__ bf16x8 pack8(float4 a, float4 b) {
    u16x8 u;
    u[0] = f2bf_rne(a.x); u[1] = f2bf_rne(a.y);
    u[2] = f2bf_rne(a.z); u[3] = f2bf_rne(a.w);
    u[4] = f2bf_rne(b.x); u[5] = f2bf_rne(b.y);
    u[6] = f2bf_rne(b.z); u[7] = f2bf_rne(b.w);
    return __builtin_bit_cast(bf16x8, u);
}

// part[kc][t][o] = sum_{k in chunk kc} x[t][k] * ternary[o][k] * scale[o*64 + k/128]
// Wave: 16 o-cols x 32 t-rows (two 16x16x32 bf16 MFMA accs), K-chunk 512.
// Round-3 counters: dur 163us, VGPR 52, Occ 40%, VALUBusy 10.8%, MfmaUtil 1%,
// 930 GB/s -> latency-bound, grid-capped at 16 waves/CU. Fixes here:
//  (a) NSPLIT 16 -> 2048 blocks = 8 blocks/CU; VGPR<=64 keeps 32 waves/CU legal.
//  (b) one-step weight prefetch (named regs, renamed by the unrolled st-loop):
//      next step's 2x int4 HBM loads are in flight during convert+MFMA.
// NO min-waves clause (round-1: forcing (256,4) spilled, +28us).
__global__ __launch_bounds__(256) void ternary_gemm(
    const int* __restrict__ tern, const float* __restrict__ scales,
    const float* __restrict__ x, float* __restrict__ part) {
    const int wave  = blockIdx.x * 4 + (threadIdx.x >> 6);
    const int lane  = threadIdx.x & 63;
    const int kc    = wave >> 9;     // 0..15  split-K chunk
    const int ntile = wave & 511;    // 0..511 o-tile
    const int n     = lane & 15;
    const int quad  = lane >> 4;
    const int o     = (ntile << 4) + n;
    const int kbase = (kc << 9) + (quad << 3);   // lane's base k within its chunk

    const int*   __restrict__ wrow = tern + (size_t)o * IN_DIM + kbase;
    const float* __restrict__ xr0  = x + n * IN_DIM + kbase;         // x row n
    const float* __restrict__ xr1  = x + (16 + n) * IN_DIM + kbase;  // x row 16+n

    // 4 contiguous group scales for this (o, kc); pipeline one group ahead.
    const float* __restrict__ sp = scales + o * (IN_DIM / GS) + (kc << 2);
    float s_cur = sp[0];

    f32x4 acc0 = {0.f, 0.f, 0.f, 0.f};
    f32x4 acc1 = {0.f, 0.f, 0.f, 0.f};

    // weight prefetch registers (step 0 of group 0)
    int4 w0 = *(const int4*)(wrow + 0);
    int4 w1 = *(const int4*)(wrow + 4);

#pragma unroll 1   // keep group loop rolled: bounds the register window
    for (int g = 0; g < 4; ++g) {
        const unsigned int p = f2bf_rne(s_cur);          // +bf16(s)
        float s_nxt = sp[(g < 3) ? (g + 1) : 3];         // prefetch (L1-hot)
#pragma unroll
        for (int st = 0; st < 4; ++st) {
            const int koff  = (g << 7) + (st << 5);      // this step's k offset
            // next step's offset; very last step re-loads itself (dead, L1-hit,
            // keeps all addresses in-bounds: max k touched stays <= 8191)
            const int knext = (st < 3) ? (koff + 32)
                                       : ((g < 3) ? ((g + 1) << 7) : koff);
            int4 nw0 = *(const int4*)(wrow + knext);     // in flight during MFMA
            int4 nw1 = *(const int4*)(wrow + knext + 4);
            float4 xf00 = *(const float4*)(xr0 + koff);
            float4 xf01 = *(const float4*)(xr0 + koff + 4);
            float4 xf10 = *(const float4*)(xr1 + koff);
            float4 xf11 = *(const float4*)(xr1 + koff + 4);
            bf16x8 a0 = pack8(xf00, xf01);
            bf16x8 a1 = pack8(xf10, xf11);
            int tw[8] = {w0.x, w0.y, w0.z, w0.w, w1.x, w1.y, w1.z, w1.w};
            bf16x8 bfr;
#pragma unroll
            for (int j = 0; j < 8; ++j) {
                int t = tw[j];
                // t in {-1,0,1}: (t & 0x8000) is the sign bit iff t==-1.
                unsigned int v = p | ((unsigned int)t & 0x8000u);
                bfr[j] = (short)((t == 0) ? 0u : v);
            }
            acc0 = __builtin_amdgcn_mfma_f32_16x16x32_bf16(a0, bfr, acc0, 0, 0, 0);
            acc1 = __builtin_amdgcn_mfma_f32_16x16x32_bf16(a1, bfr, acc1, 0, 0, 0);
            w0 = nw0; w1 = nw1;                          // SSA rename, no copy
        }
        s_cur = s_nxt;
    }

    // D layout: col = lane&15 (=o), row t = quad*4 + reg. Plain stores.
    float* __restrict__ prow = part + (size_t)kc * PART_ELEMS;
#pragma unroll
    for (int r = 0; r < 4; ++r) {
        prow[(quad * 4 + r) * OUT_DIM + o]        = acc0[r];
        prow[(quad * 4 + r + 16) * OUT_DIM + o]   = acc1[r];
    }
}

// out = sum over 16 split-K partials. 256 blocks x 256 thr x float4.
__global__ __launch_bounds__(256) void reduce_parts(const float* __restrict__ part,
                                                    float* __restrict__ out) {
    const int i = (blockIdx.x * 256 + threadIdx.x) * 4;
    float4 s = *(const float4*)(part + i);
#pragma unroll
    for (int kc = 1; kc < NSPLIT; ++kc) {
        float4 v = *(const float4*)(part + (size_t)kc * PART_ELEMS + i);
        s.x += v.x; s.y += v.y; s.z += v.z; s.w += v.w;
    }
    *(float4*)(out + i) = s;
}

extern "C" void kernel_launch(void* const* d_in, const int* in_sizes, int n_in,
                              void* d_out, int out_size, void* d_ws, size_t ws_size,
                              hipStream_t stream) {
    const float* x      = (const float*)d_in[0];
    const int*   tern   = (const int*)d_in[1];
    const float* scales = (const float*)d_in[2];
    float* out = (float*)d_out;

    float* part = (float*)d_ws;                                        // 16 MB

    ternary_gemm<<<NSPLIT * 512 / 4, 256, 0, stream>>>(tern, scales, x, part);
    reduce_parts<<<256, 256, 0, stream>>>(part, out);
}

// Round 5
// 408.455 us; speedup vs baseline: 1.0395x; 1.0225x over previous
//
#include <hip/hip_runtime.h>
#include <stdint.h>

#define OUT_DIM 8192
#define IN_DIM  8192
#define GS      128
#define MROWS   32
#define NSPLIT  8           // split-K chunks of 1024
#define KCHUNK  1024
#define KS      64          // k-ints staged per block-stage
#define NSTG    (KCHUNK / KS)   // 16
#define PART_ELEMS (MROWS * OUT_DIM)

typedef __attribute__((ext_vector_type(8))) short bf16x8;   // MFMA A/B frag (4 VGPR)
typedef __attribute__((ext_vector_type(4))) float f32x4;    // MFMA C/D frag
typedef __attribute__((ext_vector_type(8))) unsigned short u16x8;

__device__ __forceinline__ unsigned short f2bf_rne(float f) {
    uint32_t v = __builtin_bit_cast(uint32_t, f);
    v += 0x7FFFu + ((v >> 16) & 1u);
    return (unsigned short)(v >> 16);
}

// x (32x8192 fp32) -> bf16 workspace. Round-0 proven. ~3us.
__global__ __launch_bounds__(256) void prep_xbf(const float* __restrict__ x,
                                                unsigned short* __restrict__ xbf) {
    int i = (blockIdx.x * 256 + threadIdx.x) * 8;
    float4 a = *(const float4*)(x + i);
    float4 b = *(const float4*)(x + i + 4);
    float f[8] = {a.x, a.y, a.z, a.w, b.x, b.y, b.z, b.w};
    u16x8 u;
#pragma unroll
    for (int j = 0; j < 8; ++j) u[j] = f2bf_rne(f[j]);
    *(u16x8*)(xbf + i) = u;
}

// Round-4 evidence: occupancy-doubling was NULL; kernel is bound by the per-CU
// vector-memory address pipe (every load was a 64-lane gather over 16 rows,
// ~32 half-used cache lines per instr; MfmaUtil 1%, VALUBusy 11%, HBM 12%).
// Fix: block-cooperative COALESCED staging of weights into LDS (16 fully-used
// lines per instr, each weight line touched once), strided access moved to the
// LDS pipe; x read as bf16 (prep_xbf) = 16 fully-used L2-hot lines per instr.
// Block = 4 waves = 64 o-rows x 32 t. Per stage (KS=64 ints): T14 order —
// issue next stage's 4 coalesced loads -> compute current from LDS -> ds_write
// next -> barrier. Double-buffered: LDS 2*64*68*4 = 34816 B -> 4 blocks/CU,
// grid 1024 fully resident.
__global__ __launch_bounds__(256) void ternary_gemm(
    const int* __restrict__ tern, const float* __restrict__ scales,
    const unsigned short* __restrict__ xbf, float* __restrict__ part) {
    __shared__ __align__(16) int lds_w[2][64][68];   // pad 64->68: spread banks

    const int tid  = threadIdx.x;
    const int wv   = tid >> 6;
    const int lane = tid & 63;
    const int n    = lane & 15;
    const int quad = lane >> 4;

    const int otile = blockIdx.x & 127;        // 128 o-tiles of 64
    const int kc    = blockIdx.x >> 7;         // 0..7 split-K chunk
    const int o0    = otile << 6;
    const int o     = o0 + (wv << 4) + n;
    const int kpos0 = kc << 10;

    // staging coords: thread -> (4 rows, 16B col), lanes 0..15 = 256B/row contig
    const int srow = tid >> 4;                 // 0..15
    const int scol = (tid & 15) << 2;          // int col 0..60
    const int* __restrict__ wbase = tern + (size_t)o0 * IN_DIM + kpos0 + scol;

    const unsigned short* __restrict__ xr0 = xbf + n * IN_DIM + kpos0 + (quad << 3);
    const unsigned short* __restrict__ xr1 = xbf + (16 + n) * IN_DIM + kpos0 + (quad << 3);
    const float* __restrict__ sp = scales + o * (IN_DIM / GS) + (kc << 3);

    f32x4 acc0 = {0.f, 0.f, 0.f, 0.f};
    f32x4 acc1 = {0.f, 0.f, 0.f, 0.f};

    // prologue: stage 0 into buf 0
    {
        int4 s0 = *(const int4*)(wbase + (size_t)srow * IN_DIM);
        int4 s1 = *(const int4*)(wbase + (size_t)(16 + srow) * IN_DIM);
        int4 s2 = *(const int4*)(wbase + (size_t)(32 + srow) * IN_DIM);
        int4 s3 = *(const int4*)(wbase + (size_t)(48 + srow) * IN_DIM);
        *(int4*)&lds_w[0][srow][scol]      = s0;
        *(int4*)&lds_w[0][16 + srow][scol] = s1;
        *(int4*)&lds_w[0][32 + srow][scol] = s2;
        *(int4*)&lds_w[0][48 + srow][scol] = s3;
    }
    __syncthreads();

    float s_nxt = sp[0];

#pragma unroll 1
    for (int stg = 0; stg < NSTG; ++stg) {
        const int buf = stg & 1;
        // issue next stage's coalesced loads (HBM latency hides under compute)
        int4 s0, s1, s2, s3;
        if (stg < NSTG - 1) {
            const int* __restrict__ wb = wbase + (stg + 1) * KS;
            s0 = *(const int4*)(wb + (size_t)srow * IN_DIM);
            s1 = *(const int4*)(wb + (size_t)(16 + srow) * IN_DIM);
            s2 = *(const int4*)(wb + (size_t)(32 + srow) * IN_DIM);
            s3 = *(const int4*)(wb + (size_t)(48 + srow) * IN_DIM);
        }
        const float s_use  = s_nxt;
        const float s_pref = sp[(stg < NSTG - 1) ? ((stg + 1) >> 1) : 7]; // L1-hot
        const unsigned int p = f2bf_rne(s_use);      // stage's group scale (bf16)

        const int kk0  = stg * KS;
        const int lrow = (wv << 4) + n;
#pragma unroll
        for (int half = 0; half < 2; ++half) {
            const int kk = half << 5;
            int4 w0 = *(const int4*)&lds_w[buf][lrow][kk + (quad << 3)];
            int4 w1 = *(const int4*)&lds_w[buf][lrow][kk + (quad << 3) + 4];
            bf16x8 a0 = *(const bf16x8*)(xr0 + kk0 + kk);
            bf16x8 a1 = *(const bf16x8*)(xr1 + kk0 + kk);
            int tw[8] = {w0.x, w0.y, w0.z, w0.w, w1.x, w1.y, w1.z, w1.w};
            bf16x8 bfr;
#pragma unroll
            for (int j = 0; j < 8; ++j) {
                int t = tw[j];
                // t in {-1,0,1}: (t & 0x8000) is the sign bit iff t==-1.
                unsigned int v = p | ((unsigned int)t & 0x8000u);
                bfr[j] = (short)((t == 0) ? 0u : v);
            }
            acc0 = __builtin_amdgcn_mfma_f32_16x16x32_bf16(a0, bfr, acc0, 0, 0, 0);
            acc1 = __builtin_amdgcn_mfma_f32_16x16x32_bf16(a1, bfr, acc1, 0, 0, 0);
        }
        // write next stage into the other buffer (current readers unaffected)
        if (stg < NSTG - 1) {
            *(int4*)&lds_w[buf ^ 1][srow][scol]      = s0;
            *(int4*)&lds_w[buf ^ 1][16 + srow][scol] = s1;
            *(int4*)&lds_w[buf ^ 1][32 + srow][scol] = s2;
            *(int4*)&lds_w[buf ^ 1][48 + srow][scol] = s3;
        }
        __syncthreads();
        s_nxt = s_pref;
    }

    // D layout: col = lane&15 (=o), row t = quad*4 + reg. Plain stores.
    float* __restrict__ prow = part + (size_t)kc * PART_ELEMS;
#pragma unroll
    for (int r = 0; r < 4; ++r) {
        prow[(quad * 4 + r) * OUT_DIM + o]      = acc0[r];
        prow[(quad * 4 + r + 16) * OUT_DIM + o] = acc1[r];
    }
}

// out = sum over 8 split-K partials. 256 blocks x 256 thr x float4.
__global__ __launch_bounds__(256) void reduce_parts(const float* __restrict__ part,
                                                    float* __restrict__ out) {
    const int i = (blockIdx.x * 256 + threadIdx.x) * 4;
    float4 s = *(const float4*)(part + i);
#pragma unroll
    for (int kc = 1; kc < NSPLIT; ++kc) {
        float4 v = *(const float4*)(part + (size_t)kc * PART_ELEMS + i);
        s.x += v.x; s.y += v.y; s.z += v.z; s.w += v.w;
    }
    *(float4*)(out + i) = s;
}

extern "C" void kernel_launch(void* const* d_in, const int* in_sizes, int n_in,
                              void* d_out, int out_size, void* d_ws, size_t ws_size,
                              hipStream_t stream) {
    const float* x      = (const float*)d_in[0];
    const int*   tern   = (const int*)d_in[1];
    const float* scales = (const float*)d_in[2];
    float* out = (float*)d_out;

    unsigned short* xbf = (unsigned short*)d_ws;                 // 512 KB
    float* part = (float*)((char*)d_ws + (512 << 10));           // 8 MB

    prep_xbf<<<128, 256, 0, stream>>>(x, xbf);
    ternary_gemm<<<128 * NSPLIT, 256, 0, stream>>>(tern, scales, xbf, part);
    reduce_parts<<<256, 256, 0, stream>>>(part, out);
}